// Round 1
// baseline (91.467 us; speedup 1.0000x reference)
//
#include <hip/hip_runtime.h>

// OUT[n, c=j*8+k, h, w] = sum_{a,m,b} W[j,a,m,b,k] * T[n,(j+a-1)*4+m, (h-1)%28, (w+b-2)%28]
//   T[n,cc,h,w] = x[n,cc,h,w] + x[n,cc+128,h,w]
//   terms with (j+a-1) outside [0,32) are zero (channel-group zero pad)
//   terms with (w+b-1) outside [0,28) are zero (w unfold zero pad); the %28 comes from roll(+1)
// One block per (n, h_out). T row staged in LDS as [w'][ch] so the 4 m-values are one ds_read_b128.

__global__ __launch_bounds__(256) void fused_shift_conv(
    const float* __restrict__ x, const float* __restrict__ Wt, float* __restrict__ out,
    int nblk_per_n)
{
    __shared__ float T2[28][128];   // [w_src][channel 0..127]

    const int blk   = blockIdx.x;
    const int n     = blk / 28;
    const int h     = blk - n * 28;        // output h
    const int h_src = (h + 27) % 28;       // roll(+1) along h

    const int t = threadIdx.x;

    // ---- stage T = x[:128] + x[128:] for this (n, h_src) row into LDS ----
    // 128 channels x 7 float4 = 896 float4-pairs
    const float* xn = x + (size_t)n * 200704 + (size_t)h_src * 28;
    for (int idx = t; idx < 896; idx += 256) {
        const int cc = idx / 7;
        const int q  = idx - cc * 7;
        const float4 a4 = *reinterpret_cast<const float4*>(xn + cc * 784 + q * 4);
        const float4 b4 = *reinterpret_cast<const float4*>(xn + (cc + 128) * 784 + q * 4);
        const int wb = q * 4;
        T2[wb + 0][cc] = a4.x + b4.x;
        T2[wb + 1][cc] = a4.y + b4.y;
        T2[wb + 2][cc] = a4.z + b4.z;
        T2[wb + 3][cc] = a4.w + b4.w;
    }

    // ---- per-thread weights: thread t owns output channel c = t = j*8 + k ----
    const int j = t >> 3;
    const int k = t & 7;
    float wr[3][4][3];
    {
        const float* wp = Wt + j * 288 + k;   // W[j,a,m,b,k], strides 288/96/24/8/1
        #pragma unroll
        for (int a = 0; a < 3; ++a)
            #pragma unroll
            for (int m = 0; m < 4; ++m)
                #pragma unroll
                for (int b = 0; b < 3; ++b)
                    wr[a][m][b] = wp[a * 96 + m * 24 + b * 8];
    }
    // channel-group zero padding, branch-free: zero the weights, clamp g below
    if (j == 0) {
        #pragma unroll
        for (int m = 0; m < 4; ++m)
            #pragma unroll
            for (int b = 0; b < 3; ++b) wr[0][m][b] = 0.f;
    }
    if (j == 31) {
        #pragma unroll
        for (int m = 0; m < 4; ++m)
            #pragma unroll
            for (int b = 0; b < 3; ++b) wr[2][m][b] = 0.f;
    }

    __syncthreads();

    float acc[28];
    #pragma unroll
    for (int w = 0; w < 28; ++w) acc[w] = 0.f;

    // scatter form: each source column w' contributes to up to 3 outputs
    //   b=2 tap -> acc[w']        (skip w'==27: would need w+1<28)
    //   b=1 tap -> acc[(w'+1)%28] (always)
    //   b=0 tap -> acc[(w'+2)%28] (skip w'==26: would map to w=0 which needs w>=1)
    #pragma unroll
    for (int a = 0; a < 3; ++a) {
        int g = j + a - 1;
        g = g < 0 ? 0 : (g > 31 ? 31 : g);   // weights already zeroed for OOB
        const int g4 = g * 4;
        #pragma unroll
        for (int wp_ = 0; wp_ < 28; ++wp_) {
            const float4 v = *reinterpret_cast<const float4*>(&T2[wp_][g4]);
            if (wp_ != 27) {
                acc[wp_] += v.x * wr[a][0][2] + v.y * wr[a][1][2]
                          + v.z * wr[a][2][2] + v.w * wr[a][3][2];
            }
            {
                const int wo = (wp_ + 1) % 28;
                acc[wo] += v.x * wr[a][0][1] + v.y * wr[a][1][1]
                         + v.z * wr[a][2][1] + v.w * wr[a][3][1];
            }
            if (wp_ != 26) {
                const int wo = (wp_ + 2) % 28;
                acc[wo] += v.x * wr[a][0][0] + v.y * wr[a][1][0]
                         + v.z * wr[a][2][0] + v.w * wr[a][3][0];
            }
        }
    }

    // ---- write OUT[n, t, h, 0..27] : 7 aligned float4 stores ----
    float* op = out + (size_t)n * 200704 + (size_t)t * 784 + (size_t)h * 28;
    #pragma unroll
    for (int q = 0; q < 7; ++q) {
        float4 o;
        o.x = acc[q * 4 + 0];
        o.y = acc[q * 4 + 1];
        o.z = acc[q * 4 + 2];
        o.w = acc[q * 4 + 3];
        *reinterpret_cast<float4*>(op + q * 4) = o;
    }
    (void)nblk_per_n;
}

extern "C" void kernel_launch(void* const* d_in, const int* in_sizes, int n_in,
                              void* d_out, int out_size, void* d_ws, size_t ws_size,
                              hipStream_t stream) {
    const float* x  = (const float*)d_in[0];   // (128,256,28,28) f32
    const float* Wt = (const float*)d_in[1];   // (32,3,4,3,8)   f32
    float* out      = (float*)d_out;           // (128,256,28,28) f32

    const int nbatch = in_sizes[0] / 200704;   // 128
    const int grid   = nbatch * 28;            // one block per (n, h_out)

    fused_shift_conv<<<grid, 256, 0, stream>>>(x, Wt, out, 28);
}

// Round 2
// 74.356 us; speedup vs baseline: 1.2301x; 1.2301x over previous
//
#include <hip/hip_runtime.h>

typedef float __attribute__((ext_vector_type(4))) f32x4;

// OUT[n, c=j*8+k, h, w] = sum_{a,m,b} W[j,a,m,b,k] * T[n,(j+a-1)*4+m, (h-1)%28, (w+b-2)%28]
//   T[n,cc,h,w] = x[n,cc,h,w] + x[n,cc+128,h,w]
//   (j+a-1) outside [0,32) -> zero (channel-group pad); (w+b-1) outside [0,28) -> zero (w pad)
//
// One block per (n, h_out).
// Staging: global_load_lds (16B) DMA of BOTH channel halves into LDS [2][128][32]f,
//   quad-swizzled: global quad q of channel ch lands at quad-pos q' = q ^ ((ch>>2)&7).
//   DMA dest is linear (HW constraint), so the swizzle is applied to the GLOBAL source.
// Reduce: linear in-LDS pass sums the two halves (conflict-free).
// Compute: per (a,m,q) one ds_read_b128; 8 j-groups/wave hit 8 distinct quad-positions
//   -> all 32 banks -> conflict-free.

__global__ __launch_bounds__(256) void fused_shift_conv(
    const float* __restrict__ x, const float* __restrict__ Wt, float* __restrict__ out)
{
    __shared__ __align__(16) float smem[8192];   // [half][ch][32] quad-swizzled, 32 KB

    const int blk   = blockIdx.x;
    const int n     = blk / 28;
    const int h     = blk - n * 28;        // output h
    const int h_src = (h + 27) % 28;       // roll(+1) along h

    const int t    = threadIdx.x;
    const int lane = t & 63;
    const int wv   = t >> 6;

    const float* xn = x + (size_t)n * 200704 + h_src * 28;

    // ---- DMA stage: 32 chunks x 1KB; wave wv issues chunks [wv*8, wv*8+8) ----
    #pragma unroll
    for (int i = 0; i < 8; ++i) {
        const int c   = wv * 8 + i;              // chunk id 0..31 (wave-uniform)
        const int p_f = c * 256 + lane * 4;      // float index this lane fills
        const int ch2 = p_f >> 5;                // 0..255: half*128 + ch
        const int half = ch2 >> 7;
        const int ch   = ch2 & 127;
        const int qp   = (p_f >> 2) & 7;         // quad position in padded row
        int q = qp ^ ((ch >> 2) & 7);            // global quad this position holds
        q = q > 6 ? 6 : q;                       // pad position: load harmless dup
        const float* src = xn + (ch + (half << 7)) * 784 + q * 4;
        __builtin_amdgcn_global_load_lds(
            (const __attribute__((address_space(1))) void*)src,
            (__attribute__((address_space(3))) void*)&smem[c * 256],
            16, 0, 0);
    }

    // ---- per-thread weights (overlap with DMA): thread t owns c = t = j*8+k ----
    const int j = t >> 3;
    const int k = t & 7;
    float wr[3][4][3];
    {
        const float* wp = Wt + j * 288 + k;      // W[j,a,m,b,k] strides 288/96/24/8/1
        #pragma unroll
        for (int a = 0; a < 3; ++a)
            #pragma unroll
            for (int m = 0; m < 4; ++m)
                #pragma unroll
                for (int b = 0; b < 3; ++b)
                    wr[a][m][b] = wp[a * 96 + m * 24 + b * 8];
    }
    if (j == 0) {
        #pragma unroll
        for (int m = 0; m < 4; ++m)
            #pragma unroll
            for (int b = 0; b < 3; ++b) wr[0][m][b] = 0.f;
    }
    if (j == 31) {
        #pragma unroll
        for (int m = 0; m < 4; ++m)
            #pragma unroll
            for (int b = 0; b < 3; ++b) wr[2][m][b] = 0.f;
    }

    asm volatile("s_waitcnt vmcnt(0)" ::: "memory");
    __syncthreads();

    // ---- reduce: T = lo + hi, in place into lo region (linear, conflict-free) ----
    {
        f32x4* s4 = (f32x4*)smem;
        #pragma unroll
        for (int i = 0; i < 4; ++i) {
            const int Q = t + i * 256;           // 1024 sum-quads
            s4[Q] = s4[Q] + s4[Q + 1024];
        }
    }
    __syncthreads();

    // ---- compute ----
    float acc[28];
    #pragma unroll
    for (int w = 0; w < 28; ++w) acc[w] = 0.f;

    #pragma unroll
    for (int a = 0; a < 3; ++a) {
        int g = j + a - 1;
        g = g < 0 ? 0 : (g > 31 ? 31 : g);       // weights already zeroed for OOB
        const int s = g & 7;
        #pragma unroll
        for (int m = 0; m < 4; ++m) {
            const int row = (g * 4 + m) * 32;
            const float w2 = wr[a][m][2];
            const float w1 = wr[a][m][1];
            const float w0 = wr[a][m][0];
            #pragma unroll
            for (int q = 0; q < 7; ++q) {
                const f32x4 v = *(const f32x4*)&smem[row + ((q ^ s) << 2)];
                #pragma unroll
                for (int e = 0; e < 4; ++e) {
                    const int wp_ = q * 4 + e;   // source column w'
                    if (wp_ != 27) acc[wp_] += v[e] * w2;               // b=2 tap
                    acc[(wp_ + 1) % 28] += v[e] * w1;                   // b=1 tap
                    if (wp_ != 26) acc[(wp_ + 2) % 28] += v[e] * w0;    // b=0 tap
                }
            }
        }
    }

    // ---- write OUT[n, t, h, 0..27]: 7 aligned float4 stores ----
    float* op = out + (size_t)n * 200704 + (size_t)t * 784 + (size_t)h * 28;
    #pragma unroll
    for (int qq = 0; qq < 7; ++qq) {
        f32x4 o;
        o.x = acc[qq * 4 + 0];
        o.y = acc[qq * 4 + 1];
        o.z = acc[qq * 4 + 2];
        o.w = acc[qq * 4 + 3];
        *(f32x4*)(op + qq * 4) = o;
    }
}

extern "C" void kernel_launch(void* const* d_in, const int* in_sizes, int n_in,
                              void* d_out, int out_size, void* d_ws, size_t ws_size,
                              hipStream_t stream) {
    const float* x  = (const float*)d_in[0];   // (128,256,28,28) f32
    const float* Wt = (const float*)d_in[1];   // (32,3,4,3,8)   f32
    float* out      = (float*)d_out;           // (128,256,28,28) f32

    const int nbatch = in_sizes[0] / 200704;   // 128
    const int grid   = nbatch * 28;            // one block per (n, h_out)

    fused_shift_conv<<<grid, 256, 0, stream>>>(x, Wt, out);
}